// Round 8
// baseline (36.931 us; speedup 1.0000x reference)
//
#include <hip/hip_runtime.h>
#include <math.h>

#define TEMP_INV (1.0f / 0.07f)   // also the fixed LSE shift M (sims bounded by 1/T)
#define SCALE_BITS 40

typedef float vf4 __attribute__((ext_vector_type(4)));

__device__ __forceinline__ float wave_reduce_sum(float v) {
    #pragma unroll
    for (int off = 32; off; off >>= 1) v += __shfl_down(v, off);
    return v;
}

__device__ __forceinline__ float wave_reduce_max(float v) {
    #pragma unroll
    for (int off = 32; off; off >>= 1) v = fmaxf(v, __shfl_down(v, off));
    return v;
}

// fold two value-streams into one register: lanes with (lane&span) carry hi's
// partial sums, others lo's.
__device__ __forceinline__ float merge2(float lo, float hi, int span, int lane) {
    float a = lo + __shfl_xor(lo, span);
    float b = hi + __shfl_xor(hi, span);
    return (lane & span) ? b : a;
}

// Persistent kernel: (0) block0 zeroes accumulators, (1) one anchor/positive row
// per wave, (2) seg_start fill, (3) grid-strided negative chunks (4 rows/iter).
// __launch_bounds__(256,8): force <=64 VGPR -> 8 waves/SIMD (m69: occupancy
// halves at 64/128/256 VGPR).
__global__ __launch_bounds__(256, 8)
void k_main(const float* __restrict__ A, const float* __restrict__ P,
            const float* __restrict__ Ng, const int* __restrict__ idx,
            float* __restrict__ inv_na, float* __restrict__ pos_sim,
            float* __restrict__ raw, int* __restrict__ seg_start,
            unsigned long long* __restrict__ loss_acc, int* __restrict__ corr_acc,
            unsigned int* __restrict__ counter, int B, int N) {
    const int bid  = (int)blockIdx.x;
    const int wib  = threadIdx.x >> 6;
    const int lane = threadIdx.x & 63;
    const int wave = bid * 4 + wib;
    const int nwaves = (int)gridDim.x * 4;

    if (bid == 0 && threadIdx.x == 0) {   // zero accumulators for k_seg_final
        *loss_acc = 0ULL; *corr_acc = 0; *counter = 0u;
    }

    // ---- Phase 1: row stats (one row per wave; B <= nwaves) ----
    if (wave < B) {
        int b = wave;
        const float4 a = reinterpret_cast<const float4*>(A + (size_t)b * 256)[lane];
        const float4 p = reinterpret_cast<const float4*>(P + (size_t)b * 256)[lane];
        float sa = a.x * a.x + a.y * a.y + a.z * a.z + a.w * a.w;
        float sp = p.x * p.x + p.y * p.y + p.z * p.z + p.w * p.w;
        float dq = a.x * p.x + a.y * p.y + a.z * p.z + a.w * p.w;
        sa = wave_reduce_sum(sa);
        sp = wave_reduce_sum(sp);
        dq = wave_reduce_sum(dq);
        if (lane == 0) {
            float ia = 1.0f / fmaxf(sqrtf(sa), 1e-12f);
            float ip = 1.0f / fmaxf(sqrtf(sp), 1e-12f);
            inv_na[b]  = ia;
            pos_sim[b] = dq * ia * ip * TEMP_INV;
        }
    }

    // ---- Phase 2: seg_start[v] = lower_bound(idx, v), v in [0,B] ----
    {
        int t = bid * 256 + (int)threadIdx.x;
        int stride = (int)gridDim.x * 256;
        for (int j = t; j <= N; j += stride) {
            if (j == 0) {
                int c = idx[0];
                for (int v = 0; v <= c; ++v) seg_start[v] = 0;
            } else if (j < N) {
                int prev = idx[j - 1], cur = idx[j];
                for (int v = prev + 1; v <= cur; ++v) seg_start[v] = j;
            } else {
                int prev = idx[N - 1];
                for (int v = prev + 1; v <= B; ++v) seg_start[v] = N;
            }
        }
    }

    // ---- Phase 3: negative sims, 4 rows per iteration, idx prefetched ----
    const int nchunks = N >> 2;
    const float4* A4 = reinterpret_cast<const float4*>(A);
    int chunk = wave;
    if (chunk < nchunks) {
        int4 bi = *reinterpret_cast<const int4*>(idx + (chunk << 2));
        while (chunk < nchunks) {
            int nx = chunk + nwaves;
            int4 bi_n;
            if (nx < nchunks) bi_n = *reinterpret_cast<const int4*>(idx + (nx << 2));

            int j0 = chunk << 2;
            int b0 = __builtin_amdgcn_readfirstlane(bi.x);
            int b1 = __builtin_amdgcn_readfirstlane(bi.y);
            int b2 = __builtin_amdgcn_readfirstlane(bi.z);
            int b3 = __builtin_amdgcn_readfirstlane(bi.w);

            const vf4 n0 = __builtin_nontemporal_load(
                reinterpret_cast<const vf4*>(Ng + (size_t)j0 * 256) + lane);
            const vf4 n1 = __builtin_nontemporal_load(
                reinterpret_cast<const vf4*>(Ng + (size_t)(j0 + 1) * 256) + lane);
            const vf4 n2 = __builtin_nontemporal_load(
                reinterpret_cast<const vf4*>(Ng + (size_t)(j0 + 2) * 256) + lane);
            const vf4 n3 = __builtin_nontemporal_load(
                reinterpret_cast<const vf4*>(Ng + (size_t)(j0 + 3) * 256) + lane);

            float sn0 = n0.x*n0.x + n0.y*n0.y + n0.z*n0.z + n0.w*n0.w;
            float sn1 = n1.x*n1.x + n1.y*n1.y + n1.z*n1.z + n1.w*n1.w;
            float sn2 = n2.x*n2.x + n2.y*n2.y + n2.z*n2.z + n2.w*n2.w;
            float sn3 = n3.x*n3.x + n3.y*n3.y + n3.z*n3.z + n3.w*n3.w;

            // anchors consumed one at a time to keep live VGPRs low
            float dp0, dp1, dp2, dp3;
            {
                float4 a0 = A4[(size_t)b0 * 64 + lane];
                dp0 = a0.x*n0.x + a0.y*n0.y + a0.z*n0.z + a0.w*n0.w;
                if (b3 == b0) {   // wave-uniform; common (avg segment = 32)
                    dp1 = a0.x*n1.x + a0.y*n1.y + a0.z*n1.z + a0.w*n1.w;
                    dp2 = a0.x*n2.x + a0.y*n2.y + a0.z*n2.z + a0.w*n2.w;
                    dp3 = a0.x*n3.x + a0.y*n3.y + a0.z*n3.z + a0.w*n3.w;
                } else {
                    float4 a1 = A4[(size_t)b1 * 64 + lane];
                    dp1 = a1.x*n1.x + a1.y*n1.y + a1.z*n1.z + a1.w*n1.w;
                    float4 a2 = A4[(size_t)b2 * 64 + lane];
                    dp2 = a2.x*n2.x + a2.y*n2.y + a2.z*n2.z + a2.w*n2.w;
                    float4 a3 = A4[(size_t)b3 * 64 + lane];
                    dp3 = a3.x*n3.x + a3.y*n3.y + a3.z*n3.z + a3.w*n3.w;
                }
            }

            // 8-value fold: sn_r -> lane 16r, dp_r -> lane 16r+8
            float nv0 = merge2(sn0, sn2, 32, lane);
            float nv1 = merge2(dp0, dp2, 32, lane);
            float nv2 = merge2(sn1, sn3, 32, lane);
            float nv3 = merge2(dp1, dp3, 32, lane);
            float m0  = merge2(nv0, nv2, 16, lane);
            float m1  = merge2(nv1, nv3, 16, lane);
            float f   = merge2(m0,  m1,   8, lane);
            f += __shfl_xor(f, 4);
            f += __shfl_xor(f, 2);
            f += __shfl_xor(f, 1);

            float fdp = __shfl_down(f, 8);   // lane 16r receives dp_r
            if ((lane & 15) == 0) {
                int r = lane >> 4;
                raw[j0 + r] = fdp * (1.0f / fmaxf(sqrtf(f), 1e-12f)) * TEMP_INV;
            }

            chunk = nx;
            bi = bi_n;
        }
    }
}

// 64 blocks x 1024 threads: per-segment fixed-M LSE, block partials via
// integer atomics (deterministic), last block finalizes d_out.
__global__ __launch_bounds__(1024)
void k_seg_final(const float* __restrict__ raw, const int* __restrict__ seg_start,
                 const float* __restrict__ inv_na, const float* __restrict__ pos_sim,
                 unsigned long long* __restrict__ loss_acc, int* __restrict__ corr_acc,
                 unsigned int* __restrict__ counter, float* __restrict__ out, int B) {
    __shared__ float sl[16];
    __shared__ float sc[16];
    __shared__ int is_last;
    int tid = (int)threadIdx.x, lane = tid & 63, wid = tid >> 6;  // 16 waves
    int gwave = (int)blockIdx.x * 16 + wid;

    float l_part = 0.0f, c_part = 0.0f;
    #pragma unroll
    for (int k = 0; k < 4; ++k) {
        int b = gwave * 4 + k;
        if (b >= B) break;
        int s = seg_start[b];
        int e = seg_start[b + 1];
        if (e <= s) continue;
        float ps = pos_sim[b];
        float ia = inv_na[b];
        const float M = TEMP_INV;
        float mx = -INFINITY, se = 0.0f;
        for (int j = s + lane; j < e; j += 64) {
            float t = raw[j] * ia;
            mx = fmaxf(mx, t);
            se += expf(t - M);
        }
        mx = wave_reduce_max(mx);
        se = wave_reduce_sum(se);
        if (lane == 0) {
            l_part += -ps + M + logf(se + expf(ps - M));
            c_part += (ps > mx) ? 1.0f : 0.0f;
        }
    }
    if (lane == 0) { sl[wid] = l_part; sc[wid] = c_part; }
    __syncthreads();

    if (tid == 0) {
        float l = 0.0f, c = 0.0f;
        #pragma unroll
        for (int w = 0; w < 16; ++w) { l += sl[w]; c += sc[w]; }
        unsigned long long lfix =
            (unsigned long long)((double)l * (double)(1ULL << SCALE_BITS) + 0.5);
        atomicAdd(loss_acc, lfix);
        atomicAdd(corr_acc, (int)(c + 0.5f));
        __threadfence();
        unsigned int old = atomicAdd(counter, 1u);
        is_last = (old == gridDim.x - 1) ? 1 : 0;
    }
    __syncthreads();

    if (is_last && tid == 0) {
        unsigned long long lt = atomicAdd(loss_acc, 0ULL);   // atomic read
        int ct = atomicAdd(corr_acc, 0);
        out[0] = (float)((double)lt / ((double)(1ULL << SCALE_BITS) * (double)B));
        out[1] = (float)ct / (float)B;
    }
}

extern "C" void kernel_launch(void* const* d_in, const int* in_sizes, int n_in,
                              void* d_out, int out_size, void* d_ws, size_t ws_size,
                              hipStream_t stream) {
    const float* anchor    = (const float*)d_in[0];
    const float* positive  = (const float*)d_in[1];
    const float* negatives = (const float*)d_in[2];
    const int*   idx       = (const int*)d_in[3];

    const int D = 256;
    const int B = in_sizes[0] / D;   // 4096
    const int N = in_sizes[2] / D;   // 131072

    float* ws        = (float*)d_ws;
    float* raw       = ws;                      // N
    float* inv_na    = ws + N;                  // B
    float* pos_sim   = ws + N + B;              // B
    int*   seg_start = (int*)(ws + N + 2 * B);  // B + 1
    // 8-byte aligned slot for the u64 accumulator:
    size_t off = (size_t)N + 3 * B + 1;
    off = (off + 1) & ~(size_t)1;
    unsigned long long* loss_acc = (unsigned long long*)(ws + off);  // 1 u64
    int*          corr_acc = (int*)(ws + off + 2);                   // 1 int
    unsigned int* counter  = (unsigned int*)(ws + off + 3);          // 1 uint

    float* out = (float*)d_out;

    // 2048 blocks x 256 threads (8 blocks/CU target at <=64 VGPR)
    k_main<<<2048, 256, 0, stream>>>(anchor, positive, negatives, idx,
                                     inv_na, pos_sim, raw, seg_start,
                                     loss_acc, corr_acc, counter, B, N);

    k_seg_final<<<64, 1024, 0, stream>>>(raw, seg_start, inv_na, pos_sim,
                                         loss_acc, corr_acc, counter, out, B);
}

// Round 9
// 36.740 us; speedup vs baseline: 1.0052x; 1.0052x over previous
//
#include <hip/hip_runtime.h>
#include <math.h>

#define TEMP_INV (1.0f / 0.07f)   // also the fixed LSE shift M (sims bounded by 1/T)
#define SCALE_BITS 40

typedef float vf4 __attribute__((ext_vector_type(4)));

__device__ __forceinline__ float wave_reduce_sum(float v) {
    #pragma unroll
    for (int off = 32; off; off >>= 1) v += __shfl_down(v, off);
    return v;
}

__device__ __forceinline__ float wave_reduce_max(float v) {
    #pragma unroll
    for (int off = 32; off; off >>= 1) v = fmaxf(v, __shfl_down(v, off));
    return v;
}

// fold two value-streams into one register: lanes with (lane&span) carry hi's
// partial sums, others lo's.
__device__ __forceinline__ float merge2(float lo, float hi, int span, int lane) {
    float a = lo + __shfl_xor(lo, span);
    float b = hi + __shfl_xor(hi, span);
    return (lane & span) ? b : a;
}

// Persistent kernel (R7 structure: NO launch_bounds — phase 3 needs ~80 VGPR,
// capping at 64 spills the hot loop): (0) block0 zeroes accumulators,
// (1) one anchor/positive row per wave, (2) seg_start fill, (3) grid-strided
// negative chunks (4 rows / 4KB per iter).
__global__ void k_main(const float* __restrict__ A, const float* __restrict__ P,
                       const float* __restrict__ Ng, const int* __restrict__ idx,
                       float* __restrict__ inv_na, float* __restrict__ pos_sim,
                       float* __restrict__ raw, int* __restrict__ seg_start,
                       unsigned long long* __restrict__ loss_acc,
                       int* __restrict__ corr_acc,
                       unsigned int* __restrict__ counter, int B, int N) {
    const int bid  = (int)blockIdx.x;
    const int wib  = threadIdx.x >> 6;
    const int lane = threadIdx.x & 63;
    const int wave = bid * 4 + wib;
    const int nwaves = (int)gridDim.x * 4;

    if (bid == 0 && threadIdx.x == 0) {   // zero accumulators for k_seg_final
        *loss_acc = 0ULL; *corr_acc = 0; *counter = 0u;
    }

    // ---- Phase 1: row stats (one row per wave; B <= nwaves) ----
    if (wave < B) {
        int b = wave;
        const float4 a = reinterpret_cast<const float4*>(A + (size_t)b * 256)[lane];
        const float4 p = reinterpret_cast<const float4*>(P + (size_t)b * 256)[lane];
        float sa = a.x * a.x + a.y * a.y + a.z * a.z + a.w * a.w;
        float sp = p.x * p.x + p.y * p.y + p.z * p.z + p.w * p.w;
        float dq = a.x * p.x + a.y * p.y + a.z * p.z + a.w * p.w;
        sa = wave_reduce_sum(sa);
        sp = wave_reduce_sum(sp);
        dq = wave_reduce_sum(dq);
        if (lane == 0) {
            float ia = 1.0f / fmaxf(sqrtf(sa), 1e-12f);
            float ip = 1.0f / fmaxf(sqrtf(sp), 1e-12f);
            inv_na[b]  = ia;
            pos_sim[b] = dq * ia * ip * TEMP_INV;
        }
    }

    // ---- Phase 2: seg_start[v] = lower_bound(idx, v), v in [0,B] ----
    {
        int t = bid * 256 + (int)threadIdx.x;
        int stride = (int)gridDim.x * 256;
        for (int j = t; j <= N; j += stride) {
            if (j == 0) {
                int c = idx[0];
                for (int v = 0; v <= c; ++v) seg_start[v] = 0;
            } else if (j < N) {
                int prev = idx[j - 1], cur = idx[j];
                for (int v = prev + 1; v <= cur; ++v) seg_start[v] = j;
            } else {
                int prev = idx[N - 1];
                for (int v = prev + 1; v <= B; ++v) seg_start[v] = N;
            }
        }
    }

    // ---- Phase 3: negative sims, 4 rows per iteration (exact R7 body) ----
    const int nchunks = N >> 2;
    const float4* A4 = reinterpret_cast<const float4*>(A);
    for (int chunk = wave; chunk < nchunks; chunk += nwaves) {
        int j0 = chunk << 2;
        int4 bi = *reinterpret_cast<const int4*>(idx + j0);
        int b0 = __builtin_amdgcn_readfirstlane(bi.x);
        int b1 = __builtin_amdgcn_readfirstlane(bi.y);
        int b2 = __builtin_amdgcn_readfirstlane(bi.z);
        int b3 = __builtin_amdgcn_readfirstlane(bi.w);

        const vf4 n0 = __builtin_nontemporal_load(
            reinterpret_cast<const vf4*>(Ng + (size_t)j0 * 256) + lane);
        const vf4 n1 = __builtin_nontemporal_load(
            reinterpret_cast<const vf4*>(Ng + (size_t)(j0 + 1) * 256) + lane);
        const vf4 n2 = __builtin_nontemporal_load(
            reinterpret_cast<const vf4*>(Ng + (size_t)(j0 + 2) * 256) + lane);
        const vf4 n3 = __builtin_nontemporal_load(
            reinterpret_cast<const vf4*>(Ng + (size_t)(j0 + 3) * 256) + lane);

        float4 a0 = A4[(size_t)b0 * 64 + lane];
        float4 a1, a2, a3;
        if (b3 == b0) {            // wave-uniform scalar branch; common case
            a1 = a0; a2 = a0; a3 = a0;
        } else {
            a1 = A4[(size_t)b1 * 64 + lane];
            a2 = A4[(size_t)b2 * 64 + lane];
            a3 = A4[(size_t)b3 * 64 + lane];
        }

        float sn0 = n0.x*n0.x + n0.y*n0.y + n0.z*n0.z + n0.w*n0.w;
        float dp0 = a0.x*n0.x + a0.y*n0.y + a0.z*n0.z + a0.w*n0.w;
        float sn1 = n1.x*n1.x + n1.y*n1.y + n1.z*n1.z + n1.w*n1.w;
        float dp1 = a1.x*n1.x + a1.y*n1.y + a1.z*n1.z + a1.w*n1.w;
        float sn2 = n2.x*n2.x + n2.y*n2.y + n2.z*n2.z + n2.w*n2.w;
        float dp2 = a2.x*n2.x + a2.y*n2.y + a2.z*n2.z + a2.w*n2.w;
        float sn3 = n3.x*n3.x + n3.y*n3.y + n3.z*n3.z + n3.w*n3.w;
        float dp3 = a3.x*n3.x + a3.y*n3.y + a3.z*n3.z + a3.w*n3.w;

        // 8-value fold: 17 shuffles total. Final layout:
        //   sn_r -> lanes [16r,16r+8), dp_r -> lanes [16r+8,16r+16)
        float nv0 = merge2(sn0, sn2, 32, lane);
        float nv1 = merge2(dp0, dp2, 32, lane);
        float nv2 = merge2(sn1, sn3, 32, lane);
        float nv3 = merge2(dp1, dp3, 32, lane);
        float m0  = merge2(nv0, nv2, 16, lane);
        float m1  = merge2(nv1, nv3, 16, lane);
        float f   = merge2(m0,  m1,   8, lane);
        f += __shfl_xor(f, 4);
        f += __shfl_xor(f, 2);
        f += __shfl_xor(f, 1);

        float fdp = __shfl_down(f, 8);   // lane 16r receives dp_r
        if ((lane & 15) == 0) {
            int r = lane >> 4;
            raw[j0 + r] = fdp * (1.0f / fmaxf(sqrtf(f), 1e-12f)) * TEMP_INV;
        }
    }
}

// 64 blocks x 1024 threads: per-segment fixed-M LSE, block partials via
// integer atomics (bit-deterministic), last block finalizes d_out.
__global__ __launch_bounds__(1024)
void k_seg_final(const float* __restrict__ raw, const int* __restrict__ seg_start,
                 const float* __restrict__ inv_na, const float* __restrict__ pos_sim,
                 unsigned long long* __restrict__ loss_acc, int* __restrict__ corr_acc,
                 unsigned int* __restrict__ counter, float* __restrict__ out, int B) {
    __shared__ float sl[16];
    __shared__ float sc[16];
    __shared__ int is_last;
    int tid = (int)threadIdx.x, lane = tid & 63, wid = tid >> 6;  // 16 waves
    int gwave = (int)blockIdx.x * 16 + wid;

    float l_part = 0.0f, c_part = 0.0f;
    #pragma unroll
    for (int k = 0; k < 4; ++k) {
        int b = gwave * 4 + k;
        if (b >= B) break;
        int s = seg_start[b];
        int e = seg_start[b + 1];
        if (e <= s) continue;
        float ps = pos_sim[b];
        float ia = inv_na[b];
        const float M = TEMP_INV;
        float mx = -INFINITY, se = 0.0f;
        for (int j = s + lane; j < e; j += 64) {
            float t = raw[j] * ia;
            mx = fmaxf(mx, t);
            se += expf(t - M);
        }
        mx = wave_reduce_max(mx);
        se = wave_reduce_sum(se);
        if (lane == 0) {
            l_part += -ps + M + logf(se + expf(ps - M));
            c_part += (ps > mx) ? 1.0f : 0.0f;
        }
    }
    if (lane == 0) { sl[wid] = l_part; sc[wid] = c_part; }
    __syncthreads();

    if (tid == 0) {
        float l = 0.0f, c = 0.0f;
        #pragma unroll
        for (int w = 0; w < 16; ++w) { l += sl[w]; c += sc[w]; }
        unsigned long long lfix =
            (unsigned long long)((double)l * (double)(1ULL << SCALE_BITS) + 0.5);
        atomicAdd(loss_acc, lfix);
        atomicAdd(corr_acc, (int)(c + 0.5f));
        __threadfence();
        unsigned int old = atomicAdd(counter, 1u);
        is_last = (old == gridDim.x - 1) ? 1 : 0;
    }
    __syncthreads();

    if (is_last && tid == 0) {
        unsigned long long lt = atomicAdd(loss_acc, 0ULL);   // atomic read
        int ct = atomicAdd(corr_acc, 0);
        out[0] = (float)((double)lt / ((double)(1ULL << SCALE_BITS) * (double)B));
        out[1] = (float)ct / (float)B;
    }
}

extern "C" void kernel_launch(void* const* d_in, const int* in_sizes, int n_in,
                              void* d_out, int out_size, void* d_ws, size_t ws_size,
                              hipStream_t stream) {
    const float* anchor    = (const float*)d_in[0];
    const float* positive  = (const float*)d_in[1];
    const float* negatives = (const float*)d_in[2];
    const int*   idx       = (const int*)d_in[3];

    const int D = 256;
    const int B = in_sizes[0] / D;   // 4096
    const int N = in_sizes[2] / D;   // 131072

    float* ws        = (float*)d_ws;
    float* raw       = ws;                      // N
    float* inv_na    = ws + N;                  // B
    float* pos_sim   = ws + N + B;              // B
    int*   seg_start = (int*)(ws + N + 2 * B);  // B + 1
    // 8-byte aligned slot for the u64 accumulator:
    size_t off = (size_t)N + 3 * B + 1;
    off = (off + 1) & ~(size_t)1;
    unsigned long long* loss_acc = (unsigned long long*)(ws + off);  // 1 u64
    int*          corr_acc = (int*)(ws + off + 2);                   // 1 int
    unsigned int* counter  = (unsigned int*)(ws + off + 3);          // 1 uint

    float* out = (float*)d_out;

    // 2048 blocks x 256 threads = machine fill; no launch_bounds (avoid spills)
    k_main<<<2048, 256, 0, stream>>>(anchor, positive, negatives, idx,
                                     inv_na, pos_sim, raw, seg_start,
                                     loss_acc, corr_acc, counter, B, N);

    k_seg_final<<<64, 1024, 0, stream>>>(raw, seg_start, inv_na, pos_sim,
                                         loss_acc, corr_acc, counter, out, B);
}